// Round 12
// baseline (61.153 us; speedup 1.0000x reference)
//
#include <hip/hip_runtime.h>

#define B     512
#define NBG   10000
#define F     32
#define H     128
#define CHUNK 20
#define NBLK  500      // NBLK*CHUNK == NBG exactly
#define REPL  3        // measurement replicas (only set 0 consumed)
#define RB    8        // batch rows per MLP block
#define MLPBLK (B / RB)     // 64

// ---------------- Kernel A: MLP -> XT[f][b], babsT[f][b] ----------------
__global__ __launch_bounds__(128) void prep_kernel(
    const float* __restrict__ X,
    const float* __restrict__ W0, const float* __restrict__ b0,
    const float* __restrict__ W1, const float* __restrict__ b1,
    const float* __restrict__ Wout, const float* __restrict__ bout,
    float* __restrict__ XT,
    float* __restrict__ babsT)
{
    __shared__ __align__(16) float xr[RB * F];
    __shared__ __align__(16) float h0[RB * H];
    __shared__ __align__(16) float h1[RB * H];
    const int t  = threadIdx.x;
    const int r0 = blockIdx.x * RB;

    for (int i = t; i < RB * F; i += 128) {
        int r = i >> 5, f = i & 31;
        float xv = X[(r0 + r) * F + f];
        xr[r * F + f] = xv;
        XT[f * B + r0 + r] = xv;
    }
    __syncthreads();

    float acc[RB];
    #pragma unroll
    for (int r = 0; r < RB; ++r) acc[r] = b0[t];
    #pragma unroll
    for (int f4 = 0; f4 < F / 4; ++f4) {
        float wa = W0[(4*f4+0)*H + t];
        float wb = W0[(4*f4+1)*H + t];
        float wc = W0[(4*f4+2)*H + t];
        float wd = W0[(4*f4+3)*H + t];
        #pragma unroll
        for (int r = 0; r < RB; ++r) {
            float4 xv = *(const float4*)&xr[r * F + 4*f4];
            acc[r] += xv.x*wa + xv.y*wb + xv.z*wc + xv.w*wd;
        }
    }
    #pragma unroll
    for (int r = 0; r < RB; ++r) h0[r * H + t] = fmaxf(acc[r], 0.f);
    __syncthreads();

    #pragma unroll
    for (int r = 0; r < RB; ++r) acc[r] = b1[t];
    #pragma unroll 8
    for (int j4 = 0; j4 < H / 4; ++j4) {
        float wa = W1[(4*j4+0)*H + t];
        float wb = W1[(4*j4+1)*H + t];
        float wc = W1[(4*j4+2)*H + t];
        float wd = W1[(4*j4+3)*H + t];
        #pragma unroll
        for (int r = 0; r < RB; ++r) {
            float4 hv = *(const float4*)&h0[r * H + 4*j4];
            acc[r] += hv.x*wa + hv.y*wb + hv.z*wc + hv.w*wd;
        }
    }
    #pragma unroll
    for (int r = 0; r < RB; ++r) h1[r * H + t] = fmaxf(acc[r], 0.f);
    __syncthreads();

    for (int i = t; i < RB * F; i += 128) {
        int r = i >> 5, f = i & 31;
        float a = bout[f];
        #pragma unroll 8
        for (int j4 = 0; j4 < H / 4; ++j4) {
            float4 hv = *(const float4*)&h1[r * H + 4*j4];
            a += hv.x*Wout[(4*j4+0)*F + f] + hv.y*Wout[(4*j4+1)*F + f]
               + hv.z*Wout[(4*j4+2)*F + f] + hv.w*Wout[(4*j4+3)*F + f];
        }
        babsT[f * B + r0 + r] = fabsf(a);
    }
}

// ---------------- Kernel B: NW partial sums (MEASUREMENT ROUND) ----------------
// r11 structure (f-outer, d[20] accumulators, transposed LDS tile broadcast)
// with two instrumentation changes:
//   1. 256-thread blocks (half the b-range each) -> 8 blocks/CU by wave cap
//      = 2x the waves/SIMD of r11 (latency-hiding A/B test).
//   2. grid.y = 3 replicas writing disjoint psw sets (only set 0 consumed)
//      -> nw dispatch exceeds the 39us harness fills and MUST show its
//      counters (VGPR remat check, VALUBusy, Occupancy, FETCH_SIZE).
__global__ __launch_bounds__(256) void nw_partial(
    const float* __restrict__ XT,
    const float* __restrict__ babsT,
    const float* __restrict__ xbg,
    const float* __restrict__ ybg,
    float* __restrict__ psw,
    float* __restrict__ pswy)
{
    __shared__ __align__(16) float tileT[F * CHUNK];   // [32][20], 2560 B
    __shared__ float ytile[CHUNK];

    const int tid   = threadIdx.x;          // 0..255
    const int chunk = blockIdx.x >> 1;      // 0..499
    const int half  = blockIdx.x & 1;       // which half of the batch
    const int b     = half * 256 + tid;
    const int n0    = chunk * CHUNK;
    const size_t setoff = (size_t)blockIdx.y * (NBLK * B);

    // stage chunk transposed: 640 contiguous reads -> tileT[f][n]
    for (int i = tid; i < CHUNK * F; i += 256)
        tileT[(i & 31) * CHUNK + (i >> 5)] = xbg[n0 * F + i];
    if (tid < CHUNK) ytile[tid] = ybg[n0 + tid];
    __syncthreads();

    float d[CHUNK];
    #pragma unroll
    for (int j = 0; j < CHUNK; ++j) d[j] = 0.f;

    const float* __restrict__ xt = XT + b;
    const float* __restrict__ bt = babsT + b;

    #pragma unroll 2
    for (int f = 0; f < F; ++f) {
        const float xqf = xt[f * B];      // coalesced, consumed immediately
        const float bvf = bt[f * B];
        const float4* __restrict__ row = (const float4*)(tileT + f * CHUNK);
        #pragma unroll
        for (int q = 0; q < CHUNK / 4; ++q) {
            float4 v = row[q];            // lane-uniform -> LDS broadcast
            d[4*q+0] += bvf * fabsf(xqf - v.x);
            d[4*q+1] += bvf * fabsf(xqf - v.y);
            d[4*q+2] += bvf * fabsf(xqf - v.z);
            d[4*q+3] += bvf * fabsf(xqf - v.w);
        }
    }

    float sw = 0.f, swy = 0.f;
    #pragma unroll
    for (int j = 0; j < CHUNK; ++j) {
        float w = __expf(-d[j]);
        sw  += w;
        swy += w * ytile[j];
    }

    psw [setoff + chunk * B + b] = sw;    // coalesced
    pswy[setoff + chunk * B + b] = swy;
}

// ---------------- Kernel C: combine partials (set 0), normalize ----------------
__global__ __launch_bounds__(64) void nw_final(
    const float* __restrict__ psw,
    const float* __restrict__ pswy,
    float* __restrict__ out)
{
    const int b = blockIdx.x;
    const int t = threadIdx.x;

    float sw = 0.f, swy = 0.f;
    for (int c = t; c < NBLK; c += 64) {
        sw  += psw [c * B + b];
        swy += pswy[c * B + b];
    }
    #pragma unroll
    for (int off = 32; off > 0; off >>= 1) {
        sw  += __shfl_down(sw,  off);
        swy += __shfl_down(swy, off);
    }
    if (t == 0) out[b] = swy / sw;
}

extern "C" void kernel_launch(void* const* d_in, const int* in_sizes, int n_in,
                              void* d_out, int out_size, void* d_ws, size_t ws_size,
                              hipStream_t stream)
{
    const float* X    = (const float*)d_in[0];
    const float* xbg  = (const float*)d_in[1];
    const float* ybg  = (const float*)d_in[2];
    const float* W0   = (const float*)d_in[3];
    const float* b0   = (const float*)d_in[4];
    const float* W1   = (const float*)d_in[5];
    const float* b1   = (const float*)d_in[6];
    const float* Wout = (const float*)d_in[7];
    const float* bout = (const float*)d_in[8];
    float* out = (float*)d_out;

    float* XT    = (float*)d_ws;              // F*B
    float* babsT = XT + F * B;                // F*B
    float* psw   = babsT + F * B;             // REPL*NBLK*B
    float* pswy  = psw + REPL * NBLK * B;     // REPL*NBLK*B

    prep_kernel<<<MLPBLK, 128, 0, stream>>>(X, W0, b0, W1, b1, Wout, bout, XT, babsT);
    nw_partial<<<dim3(2 * NBLK, REPL), 256, 0, stream>>>(XT, babsT, xbg, ybg, psw, pswy);
    nw_final<<<B, 64, 0, stream>>>(psw, pswy, out);
}

// Round 13
// 54.165 us; speedup vs baseline: 1.1290x; 1.1290x over previous
//
#include <hip/hip_runtime.h>

#define B      512
#define NBG    10000
#define F      32
#define H      128
#define CHUNK  10
#define STRIDE 12          // padded tile row (48B, 16B-aligned)
#define NBLK   1000        // NBLK*CHUNK == NBG exactly
#define RB     8           // batch rows per MLP block
#define MLPBLK (B / RB)    // 64

// ---------------- Kernel A: MLP -> XT[f][b], babsT[f][b] ----------------
__global__ __launch_bounds__(128) void prep_kernel(
    const float* __restrict__ X,
    const float* __restrict__ W0, const float* __restrict__ b0,
    const float* __restrict__ W1, const float* __restrict__ b1,
    const float* __restrict__ Wout, const float* __restrict__ bout,
    float* __restrict__ XT,
    float* __restrict__ babsT)
{
    __shared__ __align__(16) float xr[RB * F];
    __shared__ __align__(16) float h0[RB * H];
    __shared__ __align__(16) float h1[RB * H];
    const int t  = threadIdx.x;
    const int r0 = blockIdx.x * RB;

    for (int i = t; i < RB * F; i += 128) {
        int r = i >> 5, f = i & 31;
        float xv = X[(r0 + r) * F + f];
        xr[r * F + f] = xv;
        XT[f * B + r0 + r] = xv;
    }
    __syncthreads();

    float acc[RB];
    #pragma unroll
    for (int r = 0; r < RB; ++r) acc[r] = b0[t];
    #pragma unroll
    for (int f4 = 0; f4 < F / 4; ++f4) {
        float wa = W0[(4*f4+0)*H + t];
        float wb = W0[(4*f4+1)*H + t];
        float wc = W0[(4*f4+2)*H + t];
        float wd = W0[(4*f4+3)*H + t];
        #pragma unroll
        for (int r = 0; r < RB; ++r) {
            float4 xv = *(const float4*)&xr[r * F + 4*f4];
            acc[r] += xv.x*wa + xv.y*wb + xv.z*wc + xv.w*wd;
        }
    }
    #pragma unroll
    for (int r = 0; r < RB; ++r) h0[r * H + t] = fmaxf(acc[r], 0.f);
    __syncthreads();

    #pragma unroll
    for (int r = 0; r < RB; ++r) acc[r] = b1[t];
    #pragma unroll 8
    for (int j4 = 0; j4 < H / 4; ++j4) {
        float wa = W1[(4*j4+0)*H + t];
        float wb = W1[(4*j4+1)*H + t];
        float wc = W1[(4*j4+2)*H + t];
        float wd = W1[(4*j4+3)*H + t];
        #pragma unroll
        for (int r = 0; r < RB; ++r) {
            float4 hv = *(const float4*)&h0[r * H + 4*j4];
            acc[r] += hv.x*wa + hv.y*wb + hv.z*wc + hv.w*wd;
        }
    }
    #pragma unroll
    for (int r = 0; r < RB; ++r) h1[r * H + t] = fmaxf(acc[r], 0.f);
    __syncthreads();

    for (int i = t; i < RB * F; i += 128) {
        int r = i >> 5, f = i & 31;
        float a = bout[f];
        #pragma unroll 8
        for (int j4 = 0; j4 < H / 4; ++j4) {
            float4 hv = *(const float4*)&h1[r * H + 4*j4];
            a += hv.x*Wout[(4*j4+0)*F + f] + hv.y*Wout[(4*j4+1)*F + f]
               + hv.z*Wout[(4*j4+2)*F + f] + hv.w*Wout[(4*j4+3)*F + f];
        }
        babsT[f * B + r0 + r] = fabsf(a);
    }
}

// ---------------- Kernel B: NW partial sums ----------------
// r12 structure (f-outer, small register state, transposed LDS broadcast),
// occupancy from REAL work: CHUNK=10 x half-batch split = 2000 blocks x 4
// waves = 8000 waves = 31.25/CU (r12 proved the 36us plateau was wave count:
// 3x waves -> 13.9us/work-unit, VALUBusy 64-70%).
__global__ __launch_bounds__(256) void nw_partial(
    const float* __restrict__ XT,
    const float* __restrict__ babsT,
    const float* __restrict__ xbg,
    const float* __restrict__ ybg,
    float* __restrict__ psw,
    float* __restrict__ pswy)
{
    __shared__ __align__(16) float tileT[F * STRIDE];   // [32][12], 1536 B
    __shared__ float ytile[CHUNK];

    const int tid   = threadIdx.x;          // 0..255
    const int chunk = blockIdx.x >> 1;      // 0..999
    const int half  = blockIdx.x & 1;
    const int b     = half * 256 + tid;
    const int n0    = chunk * CHUNK;

    // stage chunk transposed (320 contiguous reads); pads = 0
    {
        int i = tid;
        tileT[(i & 31) * STRIDE + (i >> 5)] = xbg[n0 * F + i];
        if (tid < CHUNK * F - 256) {
            int i2 = 256 + tid;
            tileT[(i2 & 31) * STRIDE + (i2 >> 5)] = xbg[n0 * F + i2];
        }
        if (tid >= 64 && tid < 128) {       // 64 pad slots
            int k = tid - 64;
            tileT[(k >> 1) * STRIDE + CHUNK + (k & 1)] = 0.f;
        }
        if (tid < CHUNK) ytile[tid] = ybg[n0 + tid];
    }
    __syncthreads();

    float d[STRIDE];
    #pragma unroll
    for (int j = 0; j < STRIDE; ++j) d[j] = 0.f;

    const float* __restrict__ xt = XT + b;
    const float* __restrict__ bt = babsT + b;

    #pragma unroll 2
    for (int f = 0; f < F; ++f) {
        const float xqf = xt[f * B];        // coalesced, consumed immediately
        const float bvf = bt[f * B];
        const float4* __restrict__ row = (const float4*)(tileT + f * STRIDE);
        #pragma unroll
        for (int q = 0; q < STRIDE / 4; ++q) {
            float4 v = row[q];              // lane-uniform -> LDS broadcast
            d[4*q+0] += bvf * fabsf(xqf - v.x);
            d[4*q+1] += bvf * fabsf(xqf - v.y);
            d[4*q+2] += bvf * fabsf(xqf - v.z);
            d[4*q+3] += bvf * fabsf(xqf - v.w);
        }
    }

    float sw = 0.f, swy = 0.f;
    #pragma unroll
    for (int j = 0; j < CHUNK; ++j) {       // pads d[10..11] unused
        float w = __expf(-d[j]);
        sw  += w;
        swy += w * ytile[j];
    }

    psw [chunk * B + b] = sw;               // coalesced
    pswy[chunk * B + b] = swy;
}

// ---------------- Kernel C: combine partials, normalize ----------------
__global__ __launch_bounds__(64) void nw_final(
    const float* __restrict__ psw,
    const float* __restrict__ pswy,
    float* __restrict__ out)
{
    const int b = blockIdx.x;
    const int t = threadIdx.x;

    float sw = 0.f, swy = 0.f;
    for (int c = t; c < NBLK; c += 64) {
        sw  += psw [c * B + b];
        swy += pswy[c * B + b];
    }
    #pragma unroll
    for (int off = 32; off > 0; off >>= 1) {
        sw  += __shfl_down(sw,  off);
        swy += __shfl_down(swy, off);
    }
    if (t == 0) out[b] = swy / sw;
}

extern "C" void kernel_launch(void* const* d_in, const int* in_sizes, int n_in,
                              void* d_out, int out_size, void* d_ws, size_t ws_size,
                              hipStream_t stream)
{
    const float* X    = (const float*)d_in[0];
    const float* xbg  = (const float*)d_in[1];
    const float* ybg  = (const float*)d_in[2];
    const float* W0   = (const float*)d_in[3];
    const float* b0   = (const float*)d_in[4];
    const float* W1   = (const float*)d_in[5];
    const float* b1   = (const float*)d_in[6];
    const float* Wout = (const float*)d_in[7];
    const float* bout = (const float*)d_in[8];
    float* out = (float*)d_out;

    float* XT    = (float*)d_ws;              // F*B
    float* babsT = XT + F * B;                // F*B
    float* psw   = babsT + F * B;             // NBLK*B (2 MB)
    float* pswy  = psw + NBLK * B;            // NBLK*B (2 MB)

    prep_kernel<<<MLPBLK, 128, 0, stream>>>(X, W0, b0, W1, b1, Wout, bout, XT, babsT);
    nw_partial<<<2 * NBLK, 256, 0, stream>>>(XT, babsT, xbg, ybg, psw, pswy);
    nw_final<<<B, 64, 0, stream>>>(psw, pswy, out);
}

// Round 14
// 43.417 us; speedup vs baseline: 1.4085x; 1.2476x over previous
//
#include <hip/hip_runtime.h>

#define B      512
#define NBG    10000
#define F      32
#define H      128
#define PTS    40          // points per block
#define NPG    250         // NPG*PTS == NBG
#define FG     4           // feature groups (8 features each)
#define RB     8           // batch rows per MLP block
#define MLPBLK (B / RB)    // 64

// ---------------- Kernel A: MLP -> XT[f][b], babsT[f][b] ----------------
__global__ __launch_bounds__(128) void prep_kernel(
    const float* __restrict__ X,
    const float* __restrict__ W0, const float* __restrict__ b0,
    const float* __restrict__ W1, const float* __restrict__ b1,
    const float* __restrict__ Wout, const float* __restrict__ bout,
    float* __restrict__ XT,
    float* __restrict__ babsT)
{
    __shared__ __align__(16) float xr[RB * F];
    __shared__ __align__(16) float h0[RB * H];
    __shared__ __align__(16) float h1[RB * H];
    const int t  = threadIdx.x;
    const int r0 = blockIdx.x * RB;

    for (int i = t; i < RB * F; i += 128) {
        int r = i >> 5, f = i & 31;
        float xv = X[(r0 + r) * F + f];
        xr[r * F + f] = xv;
        XT[f * B + r0 + r] = xv;
    }
    __syncthreads();

    float acc[RB];
    #pragma unroll
    for (int r = 0; r < RB; ++r) acc[r] = b0[t];
    #pragma unroll
    for (int f4 = 0; f4 < F / 4; ++f4) {
        float wa = W0[(4*f4+0)*H + t];
        float wb = W0[(4*f4+1)*H + t];
        float wc = W0[(4*f4+2)*H + t];
        float wd = W0[(4*f4+3)*H + t];
        #pragma unroll
        for (int r = 0; r < RB; ++r) {
            float4 xv = *(const float4*)&xr[r * F + 4*f4];
            acc[r] += xv.x*wa + xv.y*wb + xv.z*wc + xv.w*wd;
        }
    }
    #pragma unroll
    for (int r = 0; r < RB; ++r) h0[r * H + t] = fmaxf(acc[r], 0.f);
    __syncthreads();

    #pragma unroll
    for (int r = 0; r < RB; ++r) acc[r] = b1[t];
    #pragma unroll 8
    for (int j4 = 0; j4 < H / 4; ++j4) {
        float wa = W1[(4*j4+0)*H + t];
        float wb = W1[(4*j4+1)*H + t];
        float wc = W1[(4*j4+2)*H + t];
        float wd = W1[(4*j4+3)*H + t];
        #pragma unroll
        for (int r = 0; r < RB; ++r) {
            float4 hv = *(const float4*)&h0[r * H + 4*j4];
            acc[r] += hv.x*wa + hv.y*wb + hv.z*wc + hv.w*wd;
        }
    }
    #pragma unroll
    for (int r = 0; r < RB; ++r) h1[r * H + t] = fmaxf(acc[r], 0.f);
    __syncthreads();

    for (int i = t; i < RB * F; i += 128) {
        int r = i >> 5, f = i & 31;
        float a = bout[f];
        #pragma unroll 8
        for (int j4 = 0; j4 < H / 4; ++j4) {
            float4 hv = *(const float4*)&h1[r * H + 4*j4];
            a += hv.x*Wout[(4*j4+0)*F + f] + hv.y*Wout[(4*j4+1)*F + f]
               + hv.z*Wout[(4*j4+2)*F + f] + hv.w*Wout[(4*j4+3)*F + f];
        }
        babsT[f * B + r0 + r] = fabsf(a);
    }
}

// ---------------- Kernel B: NW partial sums, 2D (b x feature-slice) lanes ----------------
// Thread (b, fg): fg owns features fg*8..fg*8+7. Per-lane state xq[8]+bv[8]
// ~30 VGPR (allocator-safe; loaded ONCE, amortized over 40 points).
// 8 b-groups x 250 pt-groups = 2000 blocks x 4 waves = 8000 waves (31/CU).
// d reduced across fg via intra-quad shfl_xor(1,2) -> DPP adds (pure VALU).
// Tile staged row-major (no transpose); reads = 4 distinct float4 broadcasts
// per point, 16 disjoint banks, conflict-free.
__global__ __launch_bounds__(256) void nw_partial(
    const float* __restrict__ XT,
    const float* __restrict__ babsT,
    const float* __restrict__ xbg,
    const float* __restrict__ ybg,
    float* __restrict__ psw,
    float* __restrict__ pswy)
{
    __shared__ __align__(16) float tile[PTS * F];   // 5120 B, row-major
    __shared__ float ytile[PTS];

    const int tid = threadIdx.x;            // 0..255
    const int fg  = tid & 3;                // feature group
    const int bs  = tid >> 2;               // 0..63
    const int b   = blockIdx.y * 64 + bs;
    const int pg  = blockIdx.x;             // point group
    const int n0  = pg * PTS;

    // stage 1280 contiguous floats + 40 y values (coalesced, no transpose)
    #pragma unroll
    for (int i = 0; i < PTS * F / 256; ++i)
        tile[i * 256 + tid] = xbg[n0 * F + i * 256 + tid];
    if (tid < PTS) ytile[tid] = ybg[n0 + tid];

    // per-lane feature slice: 8 features, loaded once (16 regs, no remat risk)
    float xq[8], bv[8];
    #pragma unroll
    for (int k = 0; k < 8; ++k) {
        xq[k] = XT[(fg * 8 + k) * B + b];
        bv[k] = babsT[(fg * 8 + k) * B + b];
    }
    __syncthreads();

    const float4* t4 = (const float4*)tile;
    float sw = 0.f, swy = 0.f;

    #pragma unroll 4
    for (int j = 0; j < PTS; ++j) {
        float4 v0 = t4[j * 8 + fg * 2 + 0];   // 4 distinct addrs, 16-lane bcast
        float4 v1 = t4[j * 8 + fg * 2 + 1];
        float d;
        d  = bv[0] * fabsf(xq[0] - v0.x);
        d += bv[1] * fabsf(xq[1] - v0.y);
        d += bv[2] * fabsf(xq[2] - v0.z);
        d += bv[3] * fabsf(xq[3] - v0.w);
        d += bv[4] * fabsf(xq[4] - v1.x);
        d += bv[5] * fabsf(xq[5] - v1.y);
        d += bv[6] * fabsf(xq[6] - v1.z);
        d += bv[7] * fabsf(xq[7] - v1.w);
        // reduce across the 4 fg lanes (intra-quad -> DPP)
        d += __shfl_xor(d, 1);
        d += __shfl_xor(d, 2);
        float w = __expf(-d);                 // redundant x4, uniform flow
        sw  += w;
        swy += w * ytile[j];
    }

    if (fg == 0) {
        psw [pg * B + b] = sw;
        pswy[pg * B + b] = swy;
    }
}

// ---------------- Kernel C: combine partials, normalize ----------------
__global__ __launch_bounds__(64) void nw_final(
    const float* __restrict__ psw,
    const float* __restrict__ pswy,
    float* __restrict__ out)
{
    const int b = blockIdx.x;
    const int t = threadIdx.x;

    float sw = 0.f, swy = 0.f;
    for (int c = t; c < NPG; c += 64) {
        sw  += psw [c * B + b];
        swy += pswy[c * B + b];
    }
    #pragma unroll
    for (int off = 32; off > 0; off >>= 1) {
        sw  += __shfl_down(sw,  off);
        swy += __shfl_down(swy, off);
    }
    if (t == 0) out[b] = swy / sw;
}

extern "C" void kernel_launch(void* const* d_in, const int* in_sizes, int n_in,
                              void* d_out, int out_size, void* d_ws, size_t ws_size,
                              hipStream_t stream)
{
    const float* X    = (const float*)d_in[0];
    const float* xbg  = (const float*)d_in[1];
    const float* ybg  = (const float*)d_in[2];
    const float* W0   = (const float*)d_in[3];
    const float* b0   = (const float*)d_in[4];
    const float* W1   = (const float*)d_in[5];
    const float* b1   = (const float*)d_in[6];
    const float* Wout = (const float*)d_in[7];
    const float* bout = (const float*)d_in[8];
    float* out = (float*)d_out;

    float* XT    = (float*)d_ws;              // F*B
    float* babsT = XT + F * B;                // F*B
    float* psw   = babsT + F * B;             // NPG*B (0.5 MB)
    float* pswy  = psw + NPG * B;             // NPG*B (0.5 MB)

    prep_kernel<<<MLPBLK, 128, 0, stream>>>(X, W0, b0, W1, b1, Wout, bout, XT, babsT);
    nw_partial<<<dim3(NPG, RB), 256, 0, stream>>>(XT, babsT, xbg, ybg, psw, pswy);
    nw_final<<<B, 64, 0, stream>>>(psw, pswy, out);
}

// Round 16
// 38.390 us; speedup vs baseline: 1.5929x; 1.1309x over previous
//
#include <hip/hip_runtime.h>

#define B      512
#define NBG    10000
#define F      32
#define H      128
#define PTS    40          // points per block chunk
#define NPG    250         // NPG*PTS == NBG
#define RB     8           // batch rows per MLP block
#define MLPBLK (B / RB)    // 64

// quad (4-lane) sum via DPP quad_perm: xor1 [1,0,3,2]=0xB1, xor2 [2,3,0,1]=0x4E
__device__ __forceinline__ float qsum(float v) {
    int a = __builtin_amdgcn_update_dpp(0, __float_as_int(v), 0xB1, 0xF, 0xF, true);
    float v1 = v + __int_as_float(a);
    int b = __builtin_amdgcn_update_dpp(0, __float_as_int(v1), 0x4E, 0xF, 0xF, true);
    return v1 + __int_as_float(b);
}

// ---------------- Kernel A: MLP -> babsR[b][f] (row-major, same layout as X) ----------------
__global__ __launch_bounds__(128) void prep_kernel(
    const float* __restrict__ X,
    const float* __restrict__ W0, const float* __restrict__ b0,
    const float* __restrict__ W1, const float* __restrict__ b1,
    const float* __restrict__ Wout, const float* __restrict__ bout,
    float* __restrict__ babsR)
{
    __shared__ __align__(16) float xr[RB * F];
    __shared__ __align__(16) float h0[RB * H];
    __shared__ __align__(16) float h1[RB * H];
    const int t  = threadIdx.x;
    const int r0 = blockIdx.x * RB;

    for (int i = t; i < RB * F; i += 128) {
        int r = i >> 5, f = i & 31;
        xr[r * F + f] = X[(r0 + r) * F + f];
    }
    __syncthreads();

    float acc[RB];
    #pragma unroll
    for (int r = 0; r < RB; ++r) acc[r] = b0[t];
    #pragma unroll
    for (int f4 = 0; f4 < F / 4; ++f4) {
        float wa = W0[(4*f4+0)*H + t];
        float wb = W0[(4*f4+1)*H + t];
        float wc = W0[(4*f4+2)*H + t];
        float wd = W0[(4*f4+3)*H + t];
        #pragma unroll
        for (int r = 0; r < RB; ++r) {
            float4 xv = *(const float4*)&xr[r * F + 4*f4];
            acc[r] += xv.x*wa + xv.y*wb + xv.z*wc + xv.w*wd;
        }
    }
    #pragma unroll
    for (int r = 0; r < RB; ++r) h0[r * H + t] = fmaxf(acc[r], 0.f);
    __syncthreads();

    #pragma unroll
    for (int r = 0; r < RB; ++r) acc[r] = b1[t];
    #pragma unroll 8
    for (int j4 = 0; j4 < H / 4; ++j4) {
        float wa = W1[(4*j4+0)*H + t];
        float wb = W1[(4*j4+1)*H + t];
        float wc = W1[(4*j4+2)*H + t];
        float wd = W1[(4*j4+3)*H + t];
        #pragma unroll
        for (int r = 0; r < RB; ++r) {
            float4 hv = *(const float4*)&h0[r * H + 4*j4];
            acc[r] += hv.x*wa + hv.y*wb + hv.z*wc + hv.w*wd;
        }
    }
    #pragma unroll
    for (int r = 0; r < RB; ++r) h1[r * H + t] = fmaxf(acc[r], 0.f);
    __syncthreads();

    for (int i = t; i < RB * F; i += 128) {
        int r = i >> 5, f = i & 31;
        float a = bout[f];
        #pragma unroll 8
        for (int j4 = 0; j4 < H / 4; ++j4) {
            float4 hv = *(const float4*)&h1[r * H + 4*j4];
            a += hv.x*Wout[(4*j4+0)*F + f] + hv.y*Wout[(4*j4+1)*F + f]
               + hv.z*Wout[(4*j4+2)*F + f] + hv.w*Wout[(4*j4+3)*F + f];
        }
        babsR[(r0 + r) * F + f] = fabsf(a);
    }
}

// ---------------- Kernel B: NW partial sums — LDS-instruction-minimized ----------------
// Theory: r11-r14 all bound by ds_read issue (1 LDS unit/CU, ~12cy/b128; need
// >=24 VALU instr per LDS instr). This version: lane = (bs, fg-quad); lane owns
// 8 features x 2 batch rows; tile stored point-pair interleaved ttp[jp][f][p]
// so each ds_read_b128 = 2 feats x 2 pts. Per jp: 4 LDS (+0.5 y) vs ~96 VALU
// -> at the pipe crossover. d reduced over the quad via DPP (VALU pipe).
// State: xq/bv 8x float4 + d[4] + sw/swy ~ 59 VGPR, under the 64 target.
__global__ __launch_bounds__(256) void nw_partial(
    const float* __restrict__ X,       // [B][F] row-major (original input)
    const float* __restrict__ babsR,   // [B][F] row-major
    const float* __restrict__ xbg,
    const float* __restrict__ ybg,
    float* __restrict__ psw,
    float* __restrict__ pswy)
{
    __shared__ __align__(16) float ttp[PTS / 2 * F * 2];  // [20][32][2] = 1280
    __shared__ __align__(16) float ytile[PTS];

    const int tid = threadIdx.x;
    const int fg  = tid & 3;                 // quad lane: features fg*8..fg*8+7
    const int bs  = tid >> 2;                // 0..63
    const int b0i = blockIdx.y * 128 + bs;   // row 0
    const int b1i = b0i + 64;                // row 1
    const int n0  = blockIdx.x * PTS;

    // stage: read xbg linearly (coalesced), write point-pair interleaved
    for (int i = tid; i < PTS * F; i += 256) {
        int nr = i >> 5, f = i & 31;
        ttp[(nr >> 1) * 64 + f * 2 + (nr & 1)] = xbg[n0 * F + i];
    }
    if (tid < PTS) ytile[tid] = ybg[n0 + tid];

    // per-lane feature slice for 2 rows: 8 float4 vector loads, coalesced
    const float4 xqA0 = *(const float4*)&X[b0i * F + fg * 8];
    const float4 xqB0 = *(const float4*)&X[b0i * F + fg * 8 + 4];
    const float4 xqA1 = *(const float4*)&X[b1i * F + fg * 8];
    const float4 xqB1 = *(const float4*)&X[b1i * F + fg * 8 + 4];
    const float4 bvA0 = *(const float4*)&babsR[b0i * F + fg * 8];
    const float4 bvB0 = *(const float4*)&babsR[b0i * F + fg * 8 + 4];
    const float4 bvA1 = *(const float4*)&babsR[b1i * F + fg * 8];
    const float4 bvB1 = *(const float4*)&babsR[b1i * F + fg * 8 + 4];
    __syncthreads();

    const float4* t4 = (const float4*)ttp;   // 16 float4 per jp
    float sw0 = 0.f, swy0 = 0.f, sw1 = 0.f, swy1 = 0.f;

    #pragma unroll
    for (int jq = 0; jq < PTS / 4; ++jq) {
        const float4 yv = *(const float4*)&ytile[jq * 4];
        #pragma unroll
        for (int jj = 0; jj < 2; ++jj) {
            const int jp = jq * 2 + jj;
            const int base = jp * 16 + fg * 4;
            float d00 = 0.f, d10 = 0.f, d01 = 0.f, d11 = 0.f;  // d[p][r]

            // feats 0-3 of the slice (2 reads), then 4-7 (2 reads): caps live temps
            {
                float4 v0 = t4[base + 0];    // (f0,p0)(f0,p1)(f1,p0)(f1,p1)
                float4 v1 = t4[base + 1];
                d00 += bvA0.x * fabsf(xqA0.x - v0.x);
                d10 += bvA0.x * fabsf(xqA0.x - v0.y);
                d01 += bvA1.x * fabsf(xqA1.x - v0.x);
                d11 += bvA1.x * fabsf(xqA1.x - v0.y);
                d00 += bvA0.y * fabsf(xqA0.y - v0.z);
                d10 += bvA0.y * fabsf(xqA0.y - v0.w);
                d01 += bvA1.y * fabsf(xqA1.y - v0.z);
                d11 += bvA1.y * fabsf(xqA1.y - v0.w);
                d00 += bvA0.z * fabsf(xqA0.z - v1.x);
                d10 += bvA0.z * fabsf(xqA0.z - v1.y);
                d01 += bvA1.z * fabsf(xqA1.z - v1.x);
                d11 += bvA1.z * fabsf(xqA1.z - v1.y);
                d00 += bvA0.w * fabsf(xqA0.w - v1.z);
                d10 += bvA0.w * fabsf(xqA0.w - v1.w);
                d01 += bvA1.w * fabsf(xqA1.w - v1.z);
                d11 += bvA1.w * fabsf(xqA1.w - v1.w);
            }
            {
                float4 v2 = t4[base + 2];
                float4 v3 = t4[base + 3];
                d00 += bvB0.x * fabsf(xqB0.x - v2.x);
                d10 += bvB0.x * fabsf(xqB0.x - v2.y);
                d01 += bvB1.x * fabsf(xqB1.x - v2.x);
                d11 += bvB1.x * fabsf(xqB1.x - v2.y);
                d00 += bvB0.y * fabsf(xqB0.y - v2.z);
                d10 += bvB0.y * fabsf(xqB0.y - v2.w);
                d01 += bvB1.y * fabsf(xqB1.y - v2.z);
                d11 += bvB1.y * fabsf(xqB1.y - v2.w);
                d00 += bvB0.z * fabsf(xqB0.z - v3.x);
                d10 += bvB0.z * fabsf(xqB0.z - v3.y);
                d01 += bvB1.z * fabsf(xqB1.z - v3.x);
                d11 += bvB1.z * fabsf(xqB1.z - v3.y);
                d00 += bvB0.w * fabsf(xqB0.w - v3.z);
                d10 += bvB0.w * fabsf(xqB0.w - v3.w);
                d01 += bvB1.w * fabsf(xqB1.w - v3.z);
                d11 += bvB1.w * fabsf(xqB1.w - v3.w);
            }

            // reduce over quad (fg dimension) on the VALU pipe (DPP)
            d00 = qsum(d00); d10 = qsum(d10);
            d01 = qsum(d01); d11 = qsum(d11);

            const float y0 = jj ? yv.z : yv.x;
            const float y1 = jj ? yv.w : yv.y;
            float w;
            w = __expf(-d00); sw0 += w; swy0 += w * y0;
            w = __expf(-d10); sw0 += w; swy0 += w * y1;
            w = __expf(-d01); sw1 += w; swy1 += w * y0;
            w = __expf(-d11); sw1 += w; swy1 += w * y1;
        }
    }

    if (fg == 0) {
        psw [blockIdx.x * B + b0i] = sw0;
        pswy[blockIdx.x * B + b0i] = swy0;
        psw [blockIdx.x * B + b1i] = sw1;
        pswy[blockIdx.x * B + b1i] = swy1;
    }
}

// ---------------- Kernel C: combine partials, normalize ----------------
__global__ __launch_bounds__(64) void nw_final(
    const float* __restrict__ psw,
    const float* __restrict__ pswy,
    float* __restrict__ out)
{
    const int b = blockIdx.x;
    const int t = threadIdx.x;

    float sw = 0.f, swy = 0.f;
    for (int c = t; c < NPG; c += 64) {
        sw  += psw [c * B + b];
        swy += pswy[c * B + b];
    }
    #pragma unroll
    for (int off = 32; off > 0; off >>= 1) {
        sw  += __shfl_down(sw,  off);
        swy += __shfl_down(swy, off);
    }
    if (t == 0) out[b] = swy / sw;
}

extern "C" void kernel_launch(void* const* d_in, const int* in_sizes, int n_in,
                              void* d_out, int out_size, void* d_ws, size_t ws_size,
                              hipStream_t stream)
{
    const float* X    = (const float*)d_in[0];
    const float* xbg  = (const float*)d_in[1];
    const float* ybg  = (const float*)d_in[2];
    const float* W0   = (const float*)d_in[3];
    const float* b0   = (const float*)d_in[4];
    const float* W1   = (const float*)d_in[5];
    const float* b1   = (const float*)d_in[6];
    const float* Wout = (const float*)d_in[7];
    const float* bout = (const float*)d_in[8];
    float* out = (float*)d_out;

    float* babsR = (float*)d_ws;              // B*F
    float* psw   = babsR + B * F;             // NPG*B (0.5 MB)
    float* pswy  = psw + NPG * B;             // NPG*B (0.5 MB)

    prep_kernel<<<MLPBLK, 128, 0, stream>>>(X, W0, b0, W1, b1, Wout, bout, babsR);
    nw_partial<<<dim3(NPG, 4), 256, 0, stream>>>(X, babsR, xbg, ybg, psw, pswy);
    nw_final<<<B, 64, 0, stream>>>(psw, pswy, out);
}